// Round 8
// baseline (210.297 us; speedup 1.0000x reference)
//
#include <hip/hip_runtime.h>

#define BATCH 65536
#define TB 32

typedef _Float16 half8 __attribute__((ext_vector_type(8)));
typedef _Float16 half4v __attribute__((ext_vector_type(4)));
typedef _Float16 half2v __attribute__((ext_vector_type(2)));
typedef float fx4 __attribute__((ext_vector_type(4)));

// workspace layout (halves) -- unchanged from R12..R19
#define PW1B_OFF 0        // [4][256][32]  W1 base rows (k<110, pad->128)
#define PW1F_OFF 32768    // [256][32]     W1 feat rows, k-map [feat_i(15) 0 feat_j(15) 0]
#define PW2_OFF  40960    // [8][256][32]
#define PWR_OFF  106496   // [8][256][32]
#define PWH_OFF  172032   // [8][16][32]   [mean_w | lstd_w | pad]
#define WS_TOTAL 176128

__global__ __launch_bounds__(256) void prep_weights(
    const float* __restrict__ w1, const float* __restrict__ w2,
    const float* __restrict__ wr, const float* __restrict__ wm,
    const float* __restrict__ wl, _Float16* __restrict__ ws)
{
  int idx = blockIdx.x * 256 + threadIdx.x;
  if (idx < 32768) {            // pw1b
    int kk = idx & 31, n = (idx >> 5) & 255, kt = idx >> 13;
    int k = kt * 32 + kk;
    ws[idx] = (k < 110) ? (_Float16)w1[k * 256 + n] : (_Float16)0.f;
  } else if (idx < 40960) {     // pw1f
    int t = idx - 32768;
    int kk = t & 31, n = t >> 5;
    _Float16 v = (_Float16)0.f;
    if (kk < 15)                  v = (_Float16)w1[(113 + kk) * 256 + n];
    else if (kk >= 16 && kk < 31) v = (_Float16)w1[(131 + (kk - 16)) * 256 + n];
    ws[idx] = v;
  } else if (idx < 106496) {    // pw2
    int t = idx - 40960;
    int kk = t & 31, n = (t >> 5) & 255, kt = t >> 13;
    ws[idx] = (_Float16)w2[(kt * 32 + kk) * 256 + n];
  } else if (idx < 172032) {    // pwr
    int t = idx - 106496;
    int kk = t & 31, n = (t >> 5) & 255, kt = t >> 13;
    ws[idx] = (_Float16)wr[(kt * 32 + kk) * 256 + n];
  } else if (idx < WS_TOTAL) {  // pwh
    int t = idx - 172032;
    int kk = t & 31, n = (t >> 5) & 15, kt = t >> 9;
    int k = kt * 32 + kk;
    _Float16 v = (_Float16)0.f;
    if (n < 4) v = (_Float16)wm[k * 4 + n];
    else if (n < 8) v = (_Float16)wl[k * 4 + (n - 4)];
    ws[PWH_OFF + t] = v;
  }
}

// R20 = R13's 2-sweep g2 (acc[12], max weight reuse: pw2 streamed ONCE per
// group -> 32KB/wave, lowest-L2 config of the series) WITHOUT R13's spill.
// Trade curve over R13/R17/R19: pw2 traffic/wave = 16KB * 12/(acc_regs/8);
// R13 (acc48, spill) 117us < R17 (acc24) 122 < R19 (acc16, 1blk) 134.
// acc[12] is paid for by evicting the other long-lived sets from g2's range:
//  - u RECOMPUTED per group (R15 trick; 2 groups -> only +16 MFMAs total),
//    so u (16) is never live during a g2 sweep.
//  - agg carried PACKED fp16 (8 regs; proven R15/R17, absmax 0.03125).
// g2 live: acc48 + aggp8 + transients ~22 -> arch ~56-64, total ~112-120
// <= 128 -> 2 blocks/CU, no spill. Barriers stay 6. Staging/g1/g3/heads
// identical to R17 (all verified).
__global__ __launch_bounds__(512) void actor_fused(
    const float* __restrict__ obs, const float* __restrict__ lemb,
    const float* __restrict__ w1, const _Float16* __restrict__ ws,
    const float* __restrict__ b1, const float* __restrict__ b2,
    const float* __restrict__ br, const float* __restrict__ bm,
    const float* __restrict__ bl, float* __restrict__ out)
{
  __shared__ __align__(16) _Float16 H1[6 * 16 * 256]; // 48 KB: 6 tiles (pp*2+rt); tiles 0,1 later r
  __shared__ __align__(16) _Float16 Bb[32 * 256];     // 16 KB: base (K=128), then agg
  __shared__ __align__(16) _Float16 Os[3 * 32 * 16];  //  3 KB: compact obj tiles
  __shared__ __align__(16) float    Bsf[6 * 256];     //  6 KB: fused per-perm biases (f32)

  const _Float16* __restrict__ pw1b = ws + PW1B_OFF;
  const _Float16* __restrict__ pw1f = ws + PW1F_OFF;
  const _Float16* __restrict__ pw2  = ws + PW2_OFF;
  const _Float16* __restrict__ pwr  = ws + PWR_OFF;
  const _Float16* __restrict__ pwh  = ws + PWH_OFF;

  const int tid  = threadIdx.x;
  const int wave = tid >> 6;        // 0..7
  const int lane = tid & 63;
  const int q    = lane >> 4;
  const int l16  = lane & 15;
  const int colbase = wave * 32;    // this wave's 32 output cols
  const int rowbase = blockIdx.x * TB;

  const int c0_0 = colbase + q * 4;        // start col of this lane's 4-col pack, nt=0
  const int c0_1 = colbase + 16 + q * 4;   // nt=1

  // ---- stage base (32 rows x K=128) -- wave-contiguous, conflict-free ----
  for (int idx = tid; idx < 1024; idx += 512) {
    int oct = idx >> 6;          // 0..15 (= k-octet)
    int r   = (idx >> 1) & 31;   // row
    int hf  = idx & 1;           // which 4-col half of the octet
    int c   = oct * 8 + hf * 4;
    float v0, v1, v2, v3;
    if (c + 3 < 100) {
      float4 f = *(const float4*)(lemb + (rowbase + r) * 100 + c);
      v0 = f.x; v1 = f.y; v2 = f.z; v3 = f.w;
    } else {
      const float* orow = obs + (rowbase + r) * 55;
      const float* lrow = lemb + (rowbase + r) * 100;
      float t[4];
      #pragma unroll
      for (int j = 0; j < 4; ++j) {
        int cc = c + j;
        t[j] = cc < 100 ? lrow[cc] : (cc < 110 ? orow[cc - 100] : 0.f);
      }
      v0 = t[0]; v1 = t[1]; v2 = t[2]; v3 = t[3];
    }
    half4v hv = {(_Float16)v0, (_Float16)v1, (_Float16)v2, (_Float16)v3};
    *(half4v*)&Bb[(oct * 32 + r) * 8 + hf * 4] = hv;
  }
  // ---- compact obj tiles: 3 obj x 2 k-octets x 32 rows, 8B per lane ----
  for (int idx = tid; idx < 384; idx += 512) {
    int o   = idx >> 7;          // 0..2
    int k4i = (idx >> 5) & 3;    // which 4-k group
    int r   = idx & 31;
    int k0  = k4i * 4;
    const float* frow = obs + (rowbase + r) * 55 + 10 + o * 15;
    float t[4];
    #pragma unroll
    for (int j = 0; j < 4; ++j) {
      int k = k0 + j;
      t[j] = (k < 15) ? frow[k] : 0.f;
    }
    half4v hv = {(_Float16)t[0], (_Float16)t[1], (_Float16)t[2], (_Float16)t[3]};
    *(half4v*)&Os[o * 512 + ((k0 >> 3) * 32 + r) * 8 + (k0 & 7)] = hv;
  }
  // ---- fused per-perm biases (f32): b1 + W1[onehot_i row] + W1[onehot_j row] ----
  for (int idx = tid; idx < 1536; idx += 512) {
    int p = idx >> 8, c = idx & 255;
    int oi = p >> 1, oj = (1161 >> (2 * p)) & 3;
    Bsf[idx] = b1[c] + w1[(110 + oi) * 256 + c] + w1[(128 + oj) * 256 + c];
  }
  __syncthreads();  // B1

  const fx4 zero4 = {0.f, 0.f, 0.f, 0.f};

  // ---- U = (base @ W1base)^T (K=128); recomputed per group so it is never
  // live across a g2 sweep (the register cost of acc[12]) ----
  auto compute_u = [&](fx4* u) {
    u[0] = zero4; u[1] = zero4; u[2] = zero4; u[3] = zero4;
    #pragma unroll
    for (int kt = 0; kt < 4; ++kt) {
      half8 a0 = *(const half8*)&Bb[((kt * 4 + q) * 32 + l16) * 8];
      half8 a1 = *(const half8*)&Bb[((kt * 4 + q) * 32 + 16 + l16) * 8];
      #pragma unroll
      for (int nt = 0; nt < 2; ++nt) {
        half8 b = *(const half8*)&pw1b[(kt * 256 + colbase + nt * 16 + l16) * 32 + q * 8];
        u[nt]     = __builtin_amdgcn_mfma_f32_16x16x32_f16(b, a0, u[nt], 0, 0, 0);
        u[2 + nt] = __builtin_amdgcn_mfma_f32_16x16x32_f16(b, a1, u[2 + nt], 0, 0, 0);
      }
    }
  };

  // ---- GEMM1 group: h1_p = relu(U + F_p @ W1f + bias_p), perms {3g..3g+2} ----
  auto g1_group = [&](int g, const fx4* u) {
    half8 b1f0 = *(const half8*)&pw1f[(colbase + l16) * 32 + q * 8];
    half8 b1f1 = *(const half8*)&pw1f[(colbase + 16 + l16) * 32 + q * 8];
    #pragma unroll
    for (int pp = 0; pp < 3; ++pp) {
      const int p = g * 3 + pp;
      const int oi = p >> 1, oj = (1161 >> (2 * p)) & 3;
      const int o = (q < 2) ? oi : oj;   // quads 0,1 -> feat_i; 2,3 -> feat_j
      #pragma unroll
      for (int rt = 0; rt < 2; ++rt) {
        half8 af = *(const half8*)&Os[o * 512 + ((q & 1) * 32 + rt * 16 + l16) * 8];
        #pragma unroll
        for (int nt = 0; nt < 2; ++nt) {
          fx4 t = __builtin_amdgcn_mfma_f32_16x16x32_f16(nt ? b1f1 : b1f0, af,
                                                         u[rt * 2 + nt], 0, 0, 0);
          const int c0 = nt ? c0_1 : c0_0;
          fx4 bs = *(const fx4*)&Bsf[p * 256 + c0];
          half4v hv = {(_Float16)fmaxf(t[0] + bs[0], 0.f),
                       (_Float16)fmaxf(t[1] + bs[1], 0.f),
                       (_Float16)fmaxf(t[2] + bs[2], 0.f),
                       (_Float16)fmaxf(t[3] + bs[3], 0.f)};
          *(half4v*)&H1[(pp * 2 + rt) * 4096 + ((c0 >> 3) * 16 + l16) * 8 + (c0 & 7)] = hv;
        }
      }
    }
  };

  // ---- running agg, packed fp16 (8 VGPRs): aggp[rt*2+nt] ----
  half4v aggp[4];
  {
    half4v z = {(_Float16)0.f, (_Float16)0.f, (_Float16)0.f, (_Float16)0.f};
    aggp[0] = z; aggp[1] = z; aggp[2] = z; aggp[3] = z;
  }

  // ---- GEMM2 group: ONE sweep over pw2 per group, acc[12] (3p x 2rt x 2nt),
  // bias-folded init. Per kt: 2 global bb + 6 LDS a reads + 12 MFMAs. ----
  auto g2_group = [&]() {
    fx4 bv0 = *(const fx4*)&b2[c0_0];
    fx4 bv1 = *(const fx4*)&b2[c0_1];
    fx4 acc[12];  // [pp*4 + rt*2 + nt]
    #pragma unroll
    for (int i = 0; i < 12; ++i) acc[i] = (i & 1) ? bv1 : bv0;
    #pragma unroll 2
    for (int kt = 0; kt < 8; ++kt) {
      half8 bb0 = *(const half8*)&pw2[(kt * 256 + colbase + l16) * 32 + q * 8];
      half8 bb1 = *(const half8*)&pw2[(kt * 256 + colbase + 16 + l16) * 32 + q * 8];
      #pragma unroll
      for (int pp = 0; pp < 3; ++pp)
        #pragma unroll
        for (int rt = 0; rt < 2; ++rt) {
          half8 a = *(const half8*)&H1[(pp * 2 + rt) * 4096 + ((kt * 4 + q) * 16 + l16) * 8];
          acc[pp * 4 + rt * 2]     = __builtin_amdgcn_mfma_f32_16x16x32_f16(bb0, a, acc[pp * 4 + rt * 2], 0, 0, 0);
          acc[pp * 4 + rt * 2 + 1] = __builtin_amdgcn_mfma_f32_16x16x32_f16(bb1, a, acc[pp * 4 + rt * 2 + 1], 0, 0, 0);
        }
    }
    // epilogue: unpack agg, add relu of the 3 perms, repack fp16
    #pragma unroll
    for (int rt = 0; rt < 2; ++rt)
      #pragma unroll
      for (int nt = 0; nt < 2; ++nt) {
        int i = rt * 2 + nt;
        fx4 s;
        #pragma unroll
        for (int rr = 0; rr < 4; ++rr) s[rr] = (float)aggp[i][rr];
        #pragma unroll
        for (int pp = 0; pp < 3; ++pp)
          #pragma unroll
          for (int rr = 0; rr < 4; ++rr)
            s[rr] += fmaxf(acc[pp * 4 + rt * 2 + nt][rr], 0.f);
        half4v hv = {(_Float16)s[0], (_Float16)s[1], (_Float16)s[2], (_Float16)s[3]};
        aggp[i] = hv;
      }
  };

  {
    fx4 u[4];
    compute_u(u);
    g1_group(0, u);
  }
  __syncthreads();  // B2: h1 perms 0-2 ready
  g2_group();
  __syncthreads();  // B3: all H1 reads of group 0 done
  {
    fx4 u[4];
    compute_u(u);   // Bb base still intact (agg not staged yet)
    g1_group(1, u);
  }
  __syncthreads();  // B4: h1 perms 3-5 ready
  g2_group();

  // stage agg into Bb (base region dead: all waves past B4 > their last U)
  #pragma unroll
  for (int rt = 0; rt < 2; ++rt)
    #pragma unroll
    for (int nt = 0; nt < 2; ++nt) {
      const int c0 = nt ? c0_1 : c0_0;
      *(half4v*)&Bb[((c0 >> 3) * 32 + rt * 16 + l16) * 8 + (c0 & 7)] = aggp[rt * 2 + nt];
    }
  __syncthreads();  // B5: agg complete in Bb; all H1 reads done

  // ---- GEMM3: r = relu(agg @ rho + br), M=32, K=256; r -> H1 tiles 0,1 ----
  fx4 acc3[4];  // [rt*2+nt]
  {
    fx4 brv0 = *(const fx4*)&br[c0_0];
    fx4 brv1 = *(const fx4*)&br[c0_1];
    acc3[0] = brv0; acc3[1] = brv1; acc3[2] = brv0; acc3[3] = brv1;
  }
  #pragma unroll 2
  for (int kt = 0; kt < 8; ++kt) {
    half8 a0 = *(const half8*)&Bb[((kt * 4 + q) * 32 + l16) * 8];
    half8 a1 = *(const half8*)&Bb[((kt * 4 + q) * 32 + 16 + l16) * 8];
    half8 b0 = *(const half8*)&pwr[(kt * 256 + colbase + l16) * 32 + q * 8];
    half8 b1h = *(const half8*)&pwr[(kt * 256 + colbase + 16 + l16) * 32 + q * 8];
    acc3[0] = __builtin_amdgcn_mfma_f32_16x16x32_f16(b0,  a0, acc3[0], 0, 0, 0);
    acc3[1] = __builtin_amdgcn_mfma_f32_16x16x32_f16(b1h, a0, acc3[1], 0, 0, 0);
    acc3[2] = __builtin_amdgcn_mfma_f32_16x16x32_f16(b0,  a1, acc3[2], 0, 0, 0);
    acc3[3] = __builtin_amdgcn_mfma_f32_16x16x32_f16(b1h, a1, acc3[3], 0, 0, 0);
  }
  #pragma unroll
  for (int rt = 0; rt < 2; ++rt)
    #pragma unroll
    for (int nt = 0; nt < 2; ++nt) {
      const int c0 = nt ? c0_1 : c0_0;
      fx4 t = acc3[rt * 2 + nt];
      half4v hv = {(_Float16)fmaxf(t[0], 0.f), (_Float16)fmaxf(t[1], 0.f),
                   (_Float16)fmaxf(t[2], 0.f), (_Float16)fmaxf(t[3], 0.f)};
      *(half4v*)&H1[rt * 4096 + ((c0 >> 3) * 16 + l16) * 8 + (c0 & 7)] = hv;
    }
  __syncthreads();  // B6: r ready

  // ---- heads: waves 0,1 (one row-half each); swapped D -> float4 stores ----
  if (wave < 2) {
    fx4 a4 = zero4;
    #pragma unroll 2
    for (int kt = 0; kt < 8; ++kt) {
      half8 rfrag = *(const half8*)&H1[wave * 4096 + ((kt * 4 + q) * 16 + l16) * 8];
      half8 wfrag = *(const half8*)&pwh[(kt * 16 + l16) * 32 + q * 8];
      a4 = __builtin_amdgcn_mfma_f32_16x16x32_f16(wfrag, rfrag, a4, 0, 0, 0);
    }
    const int row = rowbase + wave * 16 + l16;
    if (q == 0) {            // head cols 0..3 = mean
      fx4 bm4 = *(const fx4*)bm;
      fx4 o = {a4[0] + bm4[0], a4[1] + bm4[1], a4[2] + bm4[2], a4[3] + bm4[3]};
      *(fx4*)&out[row * 4] = o;
    } else if (q == 1) {     // head cols 4..7 = log_std (clipped)
      fx4 bl4 = *(const fx4*)bl;
      fx4 o;
      #pragma unroll
      for (int rr = 0; rr < 4; ++rr) {
        float v = a4[rr] + bl4[rr];
        o[rr] = v < -20.f ? -20.f : (v > 2.f ? 2.f : v);
      }
      *(fx4*)&out[BATCH * 4 + row * 4] = o;
    }
  }
}

extern "C" void kernel_launch(void* const* d_in, const int* in_sizes, int n_in,
                              void* d_out, int out_size, void* d_ws, size_t ws_size,
                              hipStream_t stream) {
  const float* obs  = (const float*)d_in[0];
  const float* lemb = (const float*)d_in[1];
  const float* w1   = (const float*)d_in[2];
  const float* b1   = (const float*)d_in[3];
  const float* w2   = (const float*)d_in[4];
  const float* b2   = (const float*)d_in[5];
  const float* wr   = (const float*)d_in[6];
  const float* br   = (const float*)d_in[7];
  const float* wm   = (const float*)d_in[8];
  const float* bm   = (const float*)d_in[9];
  const float* wl   = (const float*)d_in[10];
  const float* bl   = (const float*)d_in[11];
  float* out = (float*)d_out;
  _Float16* ws = (_Float16*)d_ws;

  hipLaunchKernelGGL(prep_weights, dim3(WS_TOTAL / 256), dim3(256), 0, stream,
                     w1, w2, wr, wm, wl, ws);
  hipLaunchKernelGGL(actor_fused, dim3(BATCH / TB), dim3(512), 0, stream,
                     obs, lemb, w1, (const _Float16*)ws, b1, b2, br, bm, bl, out);
}

// Round 9
// 194.304 us; speedup vs baseline: 1.0823x; 1.0823x over previous
//
#include <hip/hip_runtime.h>

#define BATCH 65536
#define TB 32

typedef _Float16 half8 __attribute__((ext_vector_type(8)));
typedef _Float16 half4v __attribute__((ext_vector_type(4)));
typedef _Float16 half2v __attribute__((ext_vector_type(2)));
typedef float fx4 __attribute__((ext_vector_type(4)));

// workspace layout (halves)
#define PW1B_OFF 0        // [4][256][32]  W1 base rows (k<110, pad->128)
#define PW1F_OFF 32768    // [256][32]     W1 feat rows, k-map [feat_i(15) 0 feat_j(15) 0]
#define PW2_OFF  40960    // [8][256][32]
#define PWR_OFF  106496   // [8][256][32]
#define PWH_OFF  172032   // [8][16][32]   [mean_w | lstd_w | pad]
#define PBS_OFF  176128   // [6][256] f32  fused per-perm biases (NEW: precomputed)
#define WS_TOTAL 179200   // halves (PBS = 1536 f32 = 3072 halves)

__global__ __launch_bounds__(256) void prep_weights(
    const float* __restrict__ w1, const float* __restrict__ w2,
    const float* __restrict__ wr, const float* __restrict__ wm,
    const float* __restrict__ wl, const float* __restrict__ b1,
    _Float16* __restrict__ ws)
{
  int idx = blockIdx.x * 256 + threadIdx.x;
  if (idx < 32768) {            // pw1b
    int kk = idx & 31, n = (idx >> 5) & 255, kt = idx >> 13;
    int k = kt * 32 + kk;
    ws[idx] = (k < 110) ? (_Float16)w1[k * 256 + n] : (_Float16)0.f;
  } else if (idx < 40960) {     // pw1f
    int t = idx - 32768;
    int kk = t & 31, n = t >> 5;
    _Float16 v = (_Float16)0.f;
    if (kk < 15)                  v = (_Float16)w1[(113 + kk) * 256 + n];
    else if (kk >= 16 && kk < 31) v = (_Float16)w1[(131 + (kk - 16)) * 256 + n];
    ws[idx] = v;
  } else if (idx < 106496) {    // pw2
    int t = idx - 40960;
    int kk = t & 31, n = (t >> 5) & 255, kt = t >> 13;
    ws[idx] = (_Float16)w2[(kt * 32 + kk) * 256 + n];
  } else if (idx < 172032) {    // pwr
    int t = idx - 106496;
    int kk = t & 31, n = (t >> 5) & 255, kt = t >> 13;
    ws[idx] = (_Float16)wr[(kt * 32 + kk) * 256 + n];
  } else if (idx < 176128) {    // pwh
    int t = idx - 172032;
    int kk = t & 31, n = (t >> 5) & 15, kt = t >> 9;
    int k = kt * 32 + kk;
    _Float16 v = (_Float16)0.f;
    if (n < 4) v = (_Float16)wm[k * 4 + n];
    else if (n < 8) v = (_Float16)wl[k * 4 + (n - 4)];
    ws[PWH_OFF + (t)] = v;
  } else {                      // pbs: fused per-perm bias, f32 (NEW)
    int t = idx - 176128;       // t in [0, 3072); only first 1536 are floats
    if (t < 1536) {
      int p = t >> 8, c = t & 255;
      int oi = p >> 1, oj = (1161 >> (2 * p)) & 3;
      float* fbs = (float*)(ws + PBS_OFF);
      fbs[t] = b1[c] + w1[(110 + oi) * 256 + c] + w1[(128 + oj) * 256 + c];
    }
  }
}

// R21 = R17 (best no-spill config: 56 VGPR, 2 blocks/CU, 122us) + issue cuts.
// Family map R13-R20: acc12+spill@2blk=117, acc6@2blk=122, anything@1blk=
// 124-136; pipes all <25% busy -> binding constraint is instruction issue +
// phase latency, so R21 shaves the issue stream without touching structure:
//  (a) Bsf precomputed in prep_weights (weights are batch-static): removes
//      9 scalar global loads + 12 fadds per thread; staging = 3 f32 copies.
//  (b) s_setprio(1) around the MFMA k-loops (U/g2/g3): 2 independent blocks
//      per CU = phase diversity -> T5 condition applies.
//  (c) b2 bias loads hoisted out of the rt loop.
// Everything else byte-identical to R17 (verified absmax 0.03125).
__global__ __launch_bounds__(512) void actor_fused(
    const float* __restrict__ obs, const float* __restrict__ lemb,
    const float* __restrict__ w1, const _Float16* __restrict__ ws,
    const float* __restrict__ b1, const float* __restrict__ b2,
    const float* __restrict__ br, const float* __restrict__ bm,
    const float* __restrict__ bl, float* __restrict__ out)
{
  __shared__ __align__(16) _Float16 H1[6 * 16 * 256]; // 48 KB: 6 tiles (pp*2+rt); tiles 0,1 later r
  __shared__ __align__(16) _Float16 Bb[32 * 256];     // 16 KB: base (K=128), then agg accumulator
  __shared__ __align__(16) _Float16 Os[3 * 32 * 16];  //  3 KB: compact obj tiles
  __shared__ __align__(16) float    Bsf[6 * 256];     //  6 KB: fused per-perm biases (f32)

  const _Float16* __restrict__ pw1b = ws + PW1B_OFF;
  const _Float16* __restrict__ pw1f = ws + PW1F_OFF;
  const _Float16* __restrict__ pw2  = ws + PW2_OFF;
  const _Float16* __restrict__ pwr  = ws + PWR_OFF;
  const _Float16* __restrict__ pwh  = ws + PWH_OFF;
  const float*    __restrict__ pbs  = (const float*)(ws + PBS_OFF);

  const int tid  = threadIdx.x;
  const int wave = tid >> 6;        // 0..7
  const int lane = tid & 63;
  const int q    = lane >> 4;
  const int l16  = lane & 15;
  const int colbase = wave * 32;    // this wave's 32 output cols
  const int rowbase = blockIdx.x * TB;

  const int c0_0 = colbase + q * 4;        // start col of this lane's 4-col pack, nt=0
  const int c0_1 = colbase + 16 + q * 4;   // nt=1

  // ---- stage base (32 rows x K=128) -- wave-contiguous, conflict-free ----
  for (int idx = tid; idx < 1024; idx += 512) {
    int oct = idx >> 6;          // 0..15 (= k-octet)
    int r   = (idx >> 1) & 31;   // row
    int hf  = idx & 1;           // which 4-col half of the octet
    int c   = oct * 8 + hf * 4;
    float v0, v1, v2, v3;
    if (c + 3 < 100) {
      float4 f = *(const float4*)(lemb + (rowbase + r) * 100 + c);
      v0 = f.x; v1 = f.y; v2 = f.z; v3 = f.w;
    } else {
      const float* orow = obs + (rowbase + r) * 55;
      const float* lrow = lemb + (rowbase + r) * 100;
      float t[4];
      #pragma unroll
      for (int j = 0; j < 4; ++j) {
        int cc = c + j;
        t[j] = cc < 100 ? lrow[cc] : (cc < 110 ? orow[cc - 100] : 0.f);
      }
      v0 = t[0]; v1 = t[1]; v2 = t[2]; v3 = t[3];
    }
    half4v hv = {(_Float16)v0, (_Float16)v1, (_Float16)v2, (_Float16)v3};
    *(half4v*)&Bb[(oct * 32 + r) * 8 + hf * 4] = hv;
  }
  // ---- compact obj tiles: 3 obj x 2 k-octets x 32 rows, 8B per lane ----
  for (int idx = tid; idx < 384; idx += 512) {
    int o   = idx >> 7;          // 0..2
    int k4i = (idx >> 5) & 3;    // which 4-k group
    int r   = idx & 31;
    int k0  = k4i * 4;
    const float* frow = obs + (rowbase + r) * 55 + 10 + o * 15;
    float t[4];
    #pragma unroll
    for (int j = 0; j < 4; ++j) {
      int k = k0 + j;
      t[j] = (k < 15) ? frow[k] : 0.f;
    }
    half4v hv = {(_Float16)t[0], (_Float16)t[1], (_Float16)t[2], (_Float16)t[3]};
    *(half4v*)&Os[o * 512 + ((k0 >> 3) * 32 + r) * 8 + (k0 & 7)] = hv;
  }
  // ---- Bsf: plain copy of precomputed fused biases (3 f32 per thread) ----
  for (int idx = tid; idx < 1536; idx += 512)
    Bsf[idx] = pbs[idx];
  __syncthreads();  // B1

  const fx4 zero4 = {0.f, 0.f, 0.f, 0.f};

  // ---- U = (base @ W1base)^T tiles (K=128), computed ONCE, held in regs ----
  fx4 u[4];  // [rt*2+nt]
  u[0] = zero4; u[1] = zero4; u[2] = zero4; u[3] = zero4;
  __builtin_amdgcn_s_setprio(1);
  #pragma unroll
  for (int kt = 0; kt < 4; ++kt) {
    half8 a0 = *(const half8*)&Bb[((kt * 4 + q) * 32 + l16) * 8];
    half8 a1 = *(const half8*)&Bb[((kt * 4 + q) * 32 + 16 + l16) * 8];
    #pragma unroll
    for (int nt = 0; nt < 2; ++nt) {
      half8 b = *(const half8*)&pw1b[(kt * 256 + colbase + nt * 16 + l16) * 32 + q * 8];
      u[nt]     = __builtin_amdgcn_mfma_f32_16x16x32_f16(b, a0, u[nt], 0, 0, 0);
      u[2 + nt] = __builtin_amdgcn_mfma_f32_16x16x32_f16(b, a1, u[2 + nt], 0, 0, 0);
    }
  }
  __builtin_amdgcn_s_setprio(0);
  // no barrier: Bb not rewritten until the first g2 epilogue, which is after
  // B2 -- by then every wave is past its own U reads.

  // ---- GEMM1 group: h1_p = relu(U + F_p @ W1f + bias_p), perms {3g..3g+2} ----
  auto g1_group = [&](int g) {
    half8 b1f0 = *(const half8*)&pw1f[(colbase + l16) * 32 + q * 8];
    half8 b1f1 = *(const half8*)&pw1f[(colbase + 16 + l16) * 32 + q * 8];
    #pragma unroll
    for (int pp = 0; pp < 3; ++pp) {
      const int p = g * 3 + pp;
      const int oi = p >> 1, oj = (1161 >> (2 * p)) & 3;
      const int o = (q < 2) ? oi : oj;   // quads 0,1 -> feat_i; 2,3 -> feat_j
      #pragma unroll
      for (int rt = 0; rt < 2; ++rt) {
        half8 af = *(const half8*)&Os[o * 512 + ((q & 1) * 32 + rt * 16 + l16) * 8];
        #pragma unroll
        for (int nt = 0; nt < 2; ++nt) {
          fx4 t = __builtin_amdgcn_mfma_f32_16x16x32_f16(nt ? b1f1 : b1f0, af,
                                                         u[rt * 2 + nt], 0, 0, 0);
          const int c0 = nt ? c0_1 : c0_0;
          fx4 bs = *(const fx4*)&Bsf[p * 256 + c0];
          half4v hv = {(_Float16)fmaxf(t[0] + bs[0], 0.f),
                       (_Float16)fmaxf(t[1] + bs[1], 0.f),
                       (_Float16)fmaxf(t[2] + bs[2], 0.f),
                       (_Float16)fmaxf(t[3] + bs[3], 0.f)};
          *(half4v*)&H1[(pp * 2 + rt) * 4096 + ((c0 >> 3) * 16 + l16) * 8 + (c0 & 7)] = hv;
        }
      }
    }
  };

  // ---- GEMM2 group: rt-SPLIT -- two passes over row-halves, acc[6]=24 accum.
  // Perm-sum goes straight into Bb as fp16 RMW (first=plain store).
  fx4 bv0 = *(const fx4*)&b2[c0_0];
  fx4 bv1 = *(const fx4*)&b2[c0_1];
  auto g2_group = [&](bool first) {
    #pragma unroll
    for (int rt = 0; rt < 2; ++rt) {
      fx4 acc[6];  // [pp*2+nt]
      #pragma unroll
      for (int i = 0; i < 6; ++i) acc[i] = (i & 1) ? bv1 : bv0;
      __builtin_amdgcn_s_setprio(1);
      #pragma unroll 2
      for (int kt = 0; kt < 8; ++kt) {
        half8 bb0 = *(const half8*)&pw2[(kt * 256 + colbase + l16) * 32 + q * 8];
        half8 bb1 = *(const half8*)&pw2[(kt * 256 + colbase + 16 + l16) * 32 + q * 8];
        #pragma unroll
        for (int pp = 0; pp < 3; ++pp) {
          half8 a = *(const half8*)&H1[(pp * 2 + rt) * 4096 + ((kt * 4 + q) * 16 + l16) * 8];
          acc[pp * 2]     = __builtin_amdgcn_mfma_f32_16x16x32_f16(bb0, a, acc[pp * 2], 0, 0, 0);
          acc[pp * 2 + 1] = __builtin_amdgcn_mfma_f32_16x16x32_f16(bb1, a, acc[pp * 2 + 1], 0, 0, 0);
        }
      }
      __builtin_amdgcn_s_setprio(0);
      // epilogue: sum relu across the 3 perms, RMW into Bb (lane-owned cells)
      #pragma unroll
      for (int nt = 0; nt < 2; ++nt) {
        const int c0 = nt ? c0_1 : c0_0;
        fx4 s = zero4;
        #pragma unroll
        for (int pp = 0; pp < 3; ++pp)
          #pragma unroll
          for (int rr = 0; rr < 4; ++rr)
            s[rr] += fmaxf(acc[pp * 2 + nt][rr], 0.f);
        _Float16* cell = &Bb[((c0 >> 3) * 32 + rt * 16 + l16) * 8 + (c0 & 7)];
        if (!first) {
          half4v old = *(half4v*)cell;
          #pragma unroll
          for (int rr = 0; rr < 4; ++rr) s[rr] += (float)old[rr];
        }
        half4v hv = {(_Float16)s[0], (_Float16)s[1], (_Float16)s[2], (_Float16)s[3]};
        *(half4v*)cell = hv;
      }
    }
  };

  g1_group(0);
  __syncthreads();  // B2: h1 perms 0-2 ready (and all U reads of Bb done)
  g2_group(true);
  __syncthreads();  // B3: all H1 reads of group 0 done
  g1_group(1);
  __syncthreads();  // B4: h1 perms 3-5 ready
  g2_group(false);
  __syncthreads();  // B5: agg complete in Bb; all H1 reads done

  // ---- GEMM3: r = relu(agg @ rho + br), M=32, K=256; r -> H1 tiles 0,1 ----
  fx4 acc3[4];  // [rt*2+nt]
  {
    fx4 brv0 = *(const fx4*)&br[c0_0];
    fx4 brv1 = *(const fx4*)&br[c0_1];
    acc3[0] = brv0; acc3[1] = brv1; acc3[2] = brv0; acc3[3] = brv1;
  }
  __builtin_amdgcn_s_setprio(1);
  #pragma unroll 2
  for (int kt = 0; kt < 8; ++kt) {
    half8 a0 = *(const half8*)&Bb[((kt * 4 + q) * 32 + l16) * 8];
    half8 a1 = *(const half8*)&Bb[((kt * 4 + q) * 32 + 16 + l16) * 8];
    half8 b0 = *(const half8*)&pwr[(kt * 256 + colbase + l16) * 32 + q * 8];
    half8 b1h = *(const half8*)&pwr[(kt * 256 + colbase + 16 + l16) * 32 + q * 8];
    acc3[0] = __builtin_amdgcn_mfma_f32_16x16x32_f16(b0,  a0, acc3[0], 0, 0, 0);
    acc3[1] = __builtin_amdgcn_mfma_f32_16x16x32_f16(b1h, a0, acc3[1], 0, 0, 0);
    acc3[2] = __builtin_amdgcn_mfma_f32_16x16x32_f16(b0,  a1, acc3[2], 0, 0, 0);
    acc3[3] = __builtin_amdgcn_mfma_f32_16x16x32_f16(b1h, a1, acc3[3], 0, 0, 0);
  }
  __builtin_amdgcn_s_setprio(0);
  #pragma unroll
  for (int rt = 0; rt < 2; ++rt)
    #pragma unroll
    for (int nt = 0; nt < 2; ++nt) {
      const int c0 = nt ? c0_1 : c0_0;
      fx4 t = acc3[rt * 2 + nt];
      half4v hv = {(_Float16)fmaxf(t[0], 0.f), (_Float16)fmaxf(t[1], 0.f),
                   (_Float16)fmaxf(t[2], 0.f), (_Float16)fmaxf(t[3], 0.f)};
      *(half4v*)&H1[rt * 4096 + ((c0 >> 3) * 16 + l16) * 8 + (c0 & 7)] = hv;
    }
  __syncthreads();  // B6: r ready

  // ---- heads: waves 0,1 (one row-half each); swapped D -> float4 stores ----
  if (wave < 2) {
    fx4 a4 = zero4;
    #pragma unroll 2
    for (int kt = 0; kt < 8; ++kt) {
      half8 rfrag = *(const half8*)&H1[wave * 4096 + ((kt * 4 + q) * 16 + l16) * 8];
      half8 wfrag = *(const half8*)&pwh[(kt * 16 + l16) * 32 + q * 8];
      a4 = __builtin_amdgcn_mfma_f32_16x16x32_f16(wfrag, rfrag, a4, 0, 0, 0);
    }
    const int row = rowbase + wave * 16 + l16;
    if (q == 0) {            // head cols 0..3 = mean
      fx4 bm4 = *(const fx4*)bm;
      fx4 o = {a4[0] + bm4[0], a4[1] + bm4[1], a4[2] + bm4[2], a4[3] + bm4[3]};
      *(fx4*)&out[row * 4] = o;
    } else if (q == 1) {     // head cols 4..7 = log_std (clipped)
      fx4 bl4 = *(const fx4*)bl;
      fx4 o;
      #pragma unroll
      for (int rr = 0; rr < 4; ++rr) {
        float v = a4[rr] + bl4[rr];
        o[rr] = v < -20.f ? -20.f : (v > 2.f ? 2.f : v);
      }
      *(fx4*)&out[BATCH * 4 + row * 4] = o;
    }
  }
}

extern "C" void kernel_launch(void* const* d_in, const int* in_sizes, int n_in,
                              void* d_out, int out_size, void* d_ws, size_t ws_size,
                              hipStream_t stream) {
  const float* obs  = (const float*)d_in[0];
  const float* lemb = (const float*)d_in[1];
  const float* w1   = (const float*)d_in[2];
  const float* b1   = (const float*)d_in[3];
  const float* w2   = (const float*)d_in[4];
  const float* b2   = (const float*)d_in[5];
  const float* wr   = (const float*)d_in[6];
  const float* br   = (const float*)d_in[7];
  const float* wm   = (const float*)d_in[8];
  const float* bm   = (const float*)d_in[9];
  const float* wl   = (const float*)d_in[10];
  const float* bl   = (const float*)d_in[11];
  float* out = (float*)d_out;
  _Float16* ws = (_Float16*)d_ws;

  hipLaunchKernelGGL(prep_weights, dim3(WS_TOTAL / 256), dim3(256), 0, stream,
                     w1, w2, wr, wm, wl, b1, ws);
  hipLaunchKernelGGL(actor_fused, dim3(BATCH / TB), dim3(512), 0, stream,
                     obs, lemb, w1, (const _Float16*)ws, b1, b2, br, bm, bl, out);
}